// Round 8
// baseline (143.210 us; speedup 1.0000x reference)
//
#include <hip/hip_runtime.h>

#define NN 10000
#define NE 40000

typedef __attribute__((ext_vector_type(8))) short bf16x8;
typedef __attribute__((ext_vector_type(4))) float f32x4;
typedef __attribute__((ext_vector_type(8))) unsigned short u16x8;

__device__ inline unsigned short bf16rne(float f) {
  union { float f; unsigned u; } v; v.f = f;
  return (unsigned short)((v.u + 0x7FFFu + ((v.u >> 16) & 1u)) >> 16);
}

// ew2 [128 x 2048] f32 -> bf16 MFMA-B fragment order.
// elem j of lane l, col-tile ct, k-chunk kk = B[kk*32+(l>>4)*8+j][ct*16+(l&15)]
// at ushort index ct*2048 + kk*512 + l*8 + j.
__global__ void k_reorder(const float* __restrict__ ew2, unsigned short* __restrict__ out) {
  const int l  = threadIdx.x & 63;
  const int kk = threadIdx.x >> 6;
  const int ct = blockIdx.x;
  const int col = ct * 16 + (l & 15);
  const int g = l >> 4;
  u16x8 v;
#pragma unroll
  for (int j = 0; j < 8; ++j) v[j] = bf16rne(ew2[(kk * 32 + g * 8 + j) * 2048 + col]);
  *reinterpret_cast<u16x8*>(out + ((size_t)(ct * 2048 + kk * 512 + l * 8))) = v;
}

// ew1 [16 x 128] f32 -> bf16 B-frag, K padded to 32 with zeros. 8 col-tiles.
__global__ void k_reorder_e(const float* __restrict__ ew1, unsigned short* __restrict__ out) {
  const int l  = threadIdx.x & 63;
  const int ct = threadIdx.x >> 6;  // 512 threads -> 8 tiles
  const int g = l >> 4;
  u16x8 v;
#pragma unroll
  for (int j = 0; j < 8; ++j) {
    int k = g * 8 + j;
    v[j] = (k < 16) ? bf16rne(ew1[k * 128 + ct * 16 + (l & 15)]) : (unsigned short)0;
  }
  *reinterpret_cast<u16x8*>(out + ((size_t)(ct * 64 + l) * 8)) = v;
}

// out[n,KO] = (relu?)(xin[n,KI]) @ root[KI,KO] + bias[KO]
template <int KI, int KO, bool RELU_IN>
__global__ void k_root(const float* __restrict__ xin, const float* __restrict__ root,
                       const float* __restrict__ bias, float* __restrict__ out) {
  int idx = blockIdx.x * 256 + threadIdx.x;
  if (idx >= NN * KO) return;
  int n = idx / KO, o = idx % KO;
  float acc = bias[o];
#pragma unroll
  for (int k = 0; k < KI; ++k) {
    float v = xin[n * KI + k];
    if (RELU_IN) v = fmaxf(v, 0.f);
    acc += v * root[k * KO + o];
  }
  out[idx] = acc;
}

// Fused per-edge kernel: 64 edges/block, 4 waves, 625 blocks.
// H = relu(eattr@ew1+eb1) via MFMA; W = relu(H@ew2+eb2) fused with x[src]
// contraction. B-fragments streamed through a DEPTH-4 register pipeline
// (4 rotating buffers; consume-t / prefetch-t+4), eb2 staged in LDS so the
// only VMEM in the loop is the 4 b128 loads. Coalesced atomics (R3 pattern).
template <int CI, int CO, bool RELU_IN>
__global__ __launch_bounds__(256, 3) void k_edge(
    const int* __restrict__ src, const int* __restrict__ dst,
    const float* __restrict__ eattr,
    const unsigned short* __restrict__ ew1f, const float* __restrict__ eb1,
    const unsigned short* __restrict__ bfrag, const float* __restrict__ eb2,
    const float* __restrict__ xin, float* __restrict__ aggr) {
  constexpr int TE = 64;
  const int tid = threadIdx.x;
  const int e0 = blockIdx.x * TE;

  __shared__ int s_src[TE];
  __shared__ int s_dst[TE];
  __shared__ float s_x[CI][68];
  __shared__ float s_eb2[2048];
  __shared__ unsigned short s_hfrag[16 * 64 * 8];  // 16 KB

  if (tid < TE) { s_src[tid] = src[e0 + tid]; s_dst[tid] = dst[e0 + tid]; }
  for (int i = tid; i < CI * CO; i += 256) s_eb2[i] = eb2[i];
  __syncthreads();

  // gather x[src] -> transposed LDS
  for (int idx = tid; idx < TE * CI; idx += 256) {
    int e = idx / CI, c = idx % CI;
    float v = xin[(size_t)s_src[e] * CI + c];
    if (RELU_IN) v = fmaxf(v, 0.f);
    s_x[c][e] = v;
  }

  const int l = tid & 63, w = tid >> 6, g = l >> 4, c16 = l & 15;

  // ---- H phase via MFMA: wave w -> edge tile m=w, all 128 channels (8 MFMAs)
  {
    const int m = w;
    bf16x8 ea;
#pragma unroll
    for (int j = 0; j < 8; ++j) ea[j] = 0;
    if (g < 2) {
      const float* p = eattr + (size_t)(e0 + 16 * m + c16) * 16 + g * 8;
      f32x4 v0 = *reinterpret_cast<const f32x4*>(p);
      f32x4 v1 = *reinterpret_cast<const f32x4*>(p + 4);
#pragma unroll
      for (int j = 0; j < 4; ++j) { ea[j] = bf16rne(v0[j]); ea[4 + j] = bf16rne(v1[j]); }
    }
#pragma unroll
    for (int ct = 0; ct < 8; ++ct) {
      bf16x8 bw = *reinterpret_cast<const bf16x8*>(ew1f + (size_t)(ct * 64 + l) * 8);
      const float bb = eb1[ct * 16 + c16];
      f32x4 acc = {bb, bb, bb, bb};
      acc = __builtin_amdgcn_mfma_f32_16x16x32_bf16(ea, bw, acc, 0, 0, 0);
#pragma unroll
      for (int r = 0; r < 4; ++r) {
        const int c = ct * 16 + c16;
        s_hfrag[(((m * 4) + (c >> 5)) * 64 + ((c >> 3) & 3) * 16 + g * 4 + r) * 8 + (c & 7)] =
            bf16rne(fmaxf(acc[r], 0.f));
      }
    }
  }
  __syncthreads();

  // A fragments reg-resident (linear conflict-free b128 reads)
  bf16x8 afrag[4][4];
#pragma unroll
  for (int m = 0; m < 4; ++m)
#pragma unroll
    for (int kk = 0; kk < 4; ++kk)
      afrag[m][kk] = *reinterpret_cast<const bf16x8*>(&s_hfrag[((m * 4 + kk) * 64 + l) * 8]);

  float msg[4][4];
#pragma unroll
  for (int m = 0; m < 4; ++m)
#pragma unroll
    for (int r = 0; r < 4; ++r) msg[m][r] = 0.f;

  // per-wave t-schedule (R3):
  // L1 (CI=32): i=t, ct=t*4+w, ocol=w*16+c16
  // L2 (CI=64): i=(w>>1)+2t, ct=i*2+(w&1), ocol=(w&1)*16+c16 (i-parity split)
  const int ocol = (CI == 32) ? (w * 16 + c16) : ((w & 1) * 16 + c16);
  const bf16x8* Bb = reinterpret_cast<const bf16x8*>(bfrag);

  bf16x8 b0[4], b1[4], b2[4], b3[4];

#define PREF(T, BUF)                                                             \
  {                                                                              \
    const int i_ = (CI == 32) ? (T) : ((w >> 1) + 2 * (T));                      \
    const int ct_ = (CI == 32) ? ((T) * 4 + w) : (i_ * 2 + (w & 1));             \
    const bf16x8* bp_ = Bb + (size_t)ct_ * 256 + l;                              \
    _Pragma("unroll") for (int kk = 0; kk < 4; ++kk) BUF[kk] = bp_[kk * 64];     \
  }

#define COMP(T, BUF)                                                             \
  {                                                                              \
    const int i_ = (CI == 32) ? (T) : ((w >> 1) + 2 * (T));                      \
    const float bb = s_eb2[i_ * CO + ocol];                                      \
    _Pragma("unroll") for (int m = 0; m < 4; ++m) {                              \
      f32x4 wacc = {0.f, 0.f, 0.f, 0.f};                                         \
      _Pragma("unroll") for (int kk = 0; kk < 4; ++kk)                           \
          wacc = __builtin_amdgcn_mfma_f32_16x16x32_bf16(afrag[m][kk], BUF[kk],  \
                                                         wacc, 0, 0, 0);         \
      const f32x4 xs = *reinterpret_cast<const f32x4*>(&s_x[i_][m * 16 + g * 4]);\
      _Pragma("unroll") for (int r = 0; r < 4; ++r)                              \
          msg[m][r] += fmaxf(wacc[r] + bb, 0.f) * xs[r];                         \
    }                                                                            \
  }

  PREF(0, b0)
  PREF(1, b1)
  PREF(2, b2)
  PREF(3, b3)
#pragma unroll 1
  for (int t = 0; t < 28; t += 4) {
    COMP(t, b0)     PREF(t + 4, b0)
    COMP(t + 1, b1) PREF(t + 5, b1)
    COMP(t + 2, b2) PREF(t + 6, b2)
    COMP(t + 3, b3) PREF(t + 7, b3)
  }
  COMP(28, b0)
  COMP(29, b1)
  COMP(30, b2)
  COMP(31, b3)
#undef PREF
#undef COMP

  // coalesced atomics: per instruction, 4 edges x 16 consecutive cols (64B runs)
#pragma unroll
  for (int m = 0; m < 4; ++m)
#pragma unroll
    for (int r = 0; r < 4; ++r)
      atomicAdd(&aggr[(size_t)s_dst[m * 16 + g * 4 + r] * CO + ocol], msg[m][r]);
}

extern "C" void kernel_launch(void* const* d_in, const int* in_sizes, int n_in,
                              void* d_out, int out_size, void* d_ws, size_t ws_size,
                              hipStream_t stream) {
  const float* x       = (const float*)d_in[0];
  const int*   ei      = (const int*)d_in[1];
  const float* eattr   = (const float*)d_in[2];
  const float* l1_ew1  = (const float*)d_in[3];
  const float* l1_eb1  = (const float*)d_in[4];
  const float* l1_ew2  = (const float*)d_in[5];
  const float* l1_eb2  = (const float*)d_in[6];
  const float* l1_root = (const float*)d_in[7];
  const float* l1_bias = (const float*)d_in[8];
  const float* l2_ew1  = (const float*)d_in[9];
  const float* l2_eb1  = (const float*)d_in[10];
  const float* l2_ew2  = (const float*)d_in[11];
  const float* l2_eb2  = (const float*)d_in[12];
  const float* l2_root = (const float*)d_in[13];
  const float* l2_bias = (const float*)d_in[14];

  const int* src = ei;
  const int* dst = ei + NE;

  float* P1 = (float*)d_ws;                                // [N,64] pre-relu L1 out
  unsigned short* B1  = (unsigned short*)(P1 + NN * 64);   // 2048*128 bf16 ew2 frag
  unsigned short* B2  = B1 + 2048 * 128;
  unsigned short* B1e = B2 + 2048 * 128;                   // 8*64*8 bf16 ew1 frag
  unsigned short* B2e = B1e + 8 * 64 * 8;
  float* outf = (float*)d_out;

  k_reorder<<<128, 256, 0, stream>>>(l1_ew2, B1);
  k_reorder<<<128, 256, 0, stream>>>(l2_ew2, B2);
  k_reorder_e<<<1, 512, 0, stream>>>(l1_ew1, B1e);
  k_reorder_e<<<1, 512, 0, stream>>>(l2_ew1, B2e);

  k_root<32, 64, false><<<(NN * 64 + 255) / 256, 256, 0, stream>>>(x, l1_root, l1_bias, P1);
  k_edge<32, 64, false><<<NE / 64, 256, 0, stream>>>(src, dst, eattr, B1e, l1_eb1, B1, l1_eb2, x, P1);
  k_root<64, 32, true><<<(NN * 32 + 255) / 256, 256, 0, stream>>>(P1, l2_root, l2_bias, outf);
  k_edge<64, 32, true><<<NE / 64, 256, 0, stream>>>(src, dst, eattr, B2e, l2_eb1, B2, l2_eb2, P1, outf);
}

// Round 9
// 114.993 us; speedup vs baseline: 1.2454x; 1.2454x over previous
//
#include <hip/hip_runtime.h>

#define NN 10000
#define NE 40000

typedef __attribute__((ext_vector_type(8))) short bf16x8;
typedef __attribute__((ext_vector_type(4))) float f32x4;
typedef __attribute__((ext_vector_type(8))) unsigned short u16x8;

__device__ inline unsigned short bf16rne(float f) {
  union { float f; unsigned u; } v; v.f = f;
  return (unsigned short)((v.u + 0x7FFFu + ((v.u >> 16) & 1u)) >> 16);
}

// ew2 [128 x 2048] f32 -> bf16 MFMA-B fragment order.
// elem j of lane l, col-tile ct, k-chunk kk = B[kk*32+(l>>4)*8+j][ct*16+(l&15)]
// at ushort index ct*2048 + kk*512 + l*8 + j.
__global__ void k_reorder(const float* __restrict__ ew2, unsigned short* __restrict__ out) {
  const int l  = threadIdx.x & 63;
  const int kk = threadIdx.x >> 6;
  const int ct = blockIdx.x;
  const int col = ct * 16 + (l & 15);
  const int g = l >> 4;
  u16x8 v;
#pragma unroll
  for (int j = 0; j < 8; ++j) v[j] = bf16rne(ew2[(kk * 32 + g * 8 + j) * 2048 + col]);
  *reinterpret_cast<u16x8*>(out + ((size_t)(ct * 2048 + kk * 512 + l * 8))) = v;
}

// ew1 [16 x 128] f32 -> bf16 B-frag, K padded to 32 with zeros. 8 col-tiles.
__global__ void k_reorder_e(const float* __restrict__ ew1, unsigned short* __restrict__ out) {
  const int l  = threadIdx.x & 63;
  const int ct = threadIdx.x >> 6;  // 512 threads -> 8 tiles
  const int g = l >> 4;
  u16x8 v;
#pragma unroll
  for (int j = 0; j < 8; ++j) {
    int k = g * 8 + j;
    v[j] = (k < 16) ? bf16rne(ew1[k * 128 + ct * 16 + (l & 15)]) : (unsigned short)0;
  }
  *reinterpret_cast<u16x8*>(out + ((size_t)(ct * 64 + l) * 8)) = v;
}

// out[n,KO] = (relu?)(xin[n,KI]) @ root[KI,KO] + bias[KO]
template <int KI, int KO, bool RELU_IN>
__global__ void k_root(const float* __restrict__ xin, const float* __restrict__ root,
                       const float* __restrict__ bias, float* __restrict__ out) {
  int idx = blockIdx.x * 256 + threadIdx.x;
  if (idx >= NN * KO) return;
  int n = idx / KO, o = idx % KO;
  float acc = bias[o];
#pragma unroll
  for (int k = 0; k < KI; ++k) {
    float v = xin[n * KI + k];
    if (RELU_IN) v = fmaxf(v, 0.f);
    acc += v * root[k * KO + o];
  }
  out[idx] = acc;
}

// Fused per-edge kernel: 128 edges/block, 4 waves, 313 blocks.
// Each B-fragment load feeds 32 MFMAs (8 m-tiles) -> 2x issue work per loaded
// byte vs R3; depth-2 register pipeline now covers the L2 round-trip.
// H via MFMA; eb2 in LDS; coalesced atomics (R3 pattern), guarded for tail.
template <int CI, int CO, bool RELU_IN>
__global__ __launch_bounds__(256, 2) void k_edge(
    const int* __restrict__ src, const int* __restrict__ dst,
    const float* __restrict__ eattr,
    const unsigned short* __restrict__ ew1f, const float* __restrict__ eb1,
    const unsigned short* __restrict__ bfrag, const float* __restrict__ eb2,
    const float* __restrict__ xin, float* __restrict__ aggr) {
  constexpr int TE = 128;
  const int tid = threadIdx.x;
  const int e0 = blockIdx.x * TE;

  __shared__ int s_src[TE];
  __shared__ int s_dst[TE];
  __shared__ float s_x[CI][TE + 4];
  __shared__ float s_eb2[2048];
  __shared__ unsigned short s_hfrag[32 * 64 * 8];  // 32 KB

  if (tid < TE) {
    int e = e0 + tid; if (e >= NE) e = NE - 1;
    s_src[tid] = src[e]; s_dst[tid] = dst[e];
  }
  for (int i = tid; i < CI * CO; i += 256) s_eb2[i] = eb2[i];
  __syncthreads();

  // gather x[src] -> transposed LDS
  for (int idx = tid; idx < TE * CI; idx += 256) {
    int e = idx / CI, c = idx % CI;
    float v = xin[(size_t)s_src[e] * CI + c];
    if (RELU_IN) v = fmaxf(v, 0.f);
    s_x[c][e] = v;
  }

  const int l = tid & 63, w = tid >> 6, g = l >> 4, c16 = l & 15;

  // ---- H phase via MFMA: wave w -> m-tiles {2w, 2w+1}, all 128 channels
#pragma unroll
  for (int mm = 0; mm < 2; ++mm) {
    const int m = w * 2 + mm;
    bf16x8 ea;
#pragma unroll
    for (int j = 0; j < 8; ++j) ea[j] = 0;
    if (g < 2) {
      int ee = e0 + 16 * m + c16; if (ee >= NE) ee = NE - 1;
      const float* p = eattr + (size_t)ee * 16 + g * 8;
      f32x4 v0 = *reinterpret_cast<const f32x4*>(p);
      f32x4 v1 = *reinterpret_cast<const f32x4*>(p + 4);
#pragma unroll
      for (int j = 0; j < 4; ++j) { ea[j] = bf16rne(v0[j]); ea[4 + j] = bf16rne(v1[j]); }
    }
#pragma unroll
    for (int ct = 0; ct < 8; ++ct) {
      bf16x8 bw = *reinterpret_cast<const bf16x8*>(ew1f + (size_t)(ct * 64 + l) * 8);
      const float bb = eb1[ct * 16 + c16];
      f32x4 acc = {bb, bb, bb, bb};
      acc = __builtin_amdgcn_mfma_f32_16x16x32_bf16(ea, bw, acc, 0, 0, 0);
#pragma unroll
      for (int r = 0; r < 4; ++r) {
        const int c = ct * 16 + c16;
        s_hfrag[(((m * 4) + (c >> 5)) * 64 + ((c >> 3) & 3) * 16 + g * 4 + r) * 8 + (c & 7)] =
            bf16rne(fmaxf(acc[r], 0.f));
      }
    }
  }
  __syncthreads();

  // A fragments reg-resident (8 m-tiles x 4 k-chunks; AGPR-backed)
  bf16x8 afrag[8][4];
#pragma unroll
  for (int m = 0; m < 8; ++m)
#pragma unroll
    for (int kk = 0; kk < 4; ++kk)
      afrag[m][kk] = *reinterpret_cast<const bf16x8*>(&s_hfrag[((m * 4 + kk) * 64 + l) * 8]);

  float msg[8][4];
#pragma unroll
  for (int m = 0; m < 8; ++m)
#pragma unroll
    for (int r = 0; r < 4; ++r) msg[m][r] = 0.f;

  // per-wave t-schedule (R3):
  // L1 (CI=32): i=t, ct=t*4+w, ocol=w*16+c16
  // L2 (CI=64): i=(w>>1)+2t, ct=i*2+(w&1), ocol=(w&1)*16+c16 (i-parity split)
  const int ocol = (CI == 32) ? (w * 16 + c16) : ((w & 1) * 16 + c16);
  const bf16x8* Bb = reinterpret_cast<const bf16x8*>(bfrag);

  bf16x8 bA[4], bB[4];

#define PREF(T, BUF)                                                             \
  {                                                                              \
    const int i_ = (CI == 32) ? (T) : ((w >> 1) + 2 * (T));                      \
    const int ct_ = (CI == 32) ? ((T) * 4 + w) : (i_ * 2 + (w & 1));             \
    const bf16x8* bp_ = Bb + (size_t)ct_ * 256 + l;                              \
    _Pragma("unroll") for (int kk = 0; kk < 4; ++kk) BUF[kk] = bp_[kk * 64];     \
  }

#define COMP(T, BUF)                                                             \
  {                                                                              \
    const int i_ = (CI == 32) ? (T) : ((w >> 1) + 2 * (T));                      \
    const float bb = s_eb2[i_ * CO + ocol];                                      \
    _Pragma("unroll") for (int m = 0; m < 8; ++m) {                              \
      f32x4 wacc = {0.f, 0.f, 0.f, 0.f};                                         \
      _Pragma("unroll") for (int kk = 0; kk < 4; ++kk)                           \
          wacc = __builtin_amdgcn_mfma_f32_16x16x32_bf16(afrag[m][kk], BUF[kk],  \
                                                         wacc, 0, 0, 0);         \
      const f32x4 xs = *reinterpret_cast<const f32x4*>(&s_x[i_][m * 16 + g * 4]);\
      _Pragma("unroll") for (int r = 0; r < 4; ++r)                              \
          msg[m][r] += fmaxf(wacc[r] + bb, 0.f) * xs[r];                         \
    }                                                                            \
  }

  PREF(0, bA)
#pragma unroll 1
  for (int t = 0; t < 30; t += 2) {
    PREF(t + 1, bB)
    COMP(t, bA)
    PREF(t + 2, bA)
    COMP(t + 1, bB)
  }
  PREF(31, bB)
  COMP(30, bA)
  COMP(31, bB)
#undef PREF
#undef COMP

  // coalesced atomics: per instruction, 4 edges x 16 consecutive cols (64B runs)
#pragma unroll
  for (int m = 0; m < 8; ++m)
#pragma unroll
    for (int r = 0; r < 4; ++r) {
      const int eidx = m * 16 + g * 4 + r;
      if (e0 + eidx < NE)
        atomicAdd(&aggr[(size_t)s_dst[eidx] * CO + ocol], msg[m][r]);
    }
}

extern "C" void kernel_launch(void* const* d_in, const int* in_sizes, int n_in,
                              void* d_out, int out_size, void* d_ws, size_t ws_size,
                              hipStream_t stream) {
  const float* x       = (const float*)d_in[0];
  const int*   ei      = (const int*)d_in[1];
  const float* eattr   = (const float*)d_in[2];
  const float* l1_ew1  = (const float*)d_in[3];
  const float* l1_eb1  = (const float*)d_in[4];
  const float* l1_ew2  = (const float*)d_in[5];
  const float* l1_eb2  = (const float*)d_in[6];
  const float* l1_root = (const float*)d_in[7];
  const float* l1_bias = (const float*)d_in[8];
  const float* l2_ew1  = (const float*)d_in[9];
  const float* l2_eb1  = (const float*)d_in[10];
  const float* l2_ew2  = (const float*)d_in[11];
  const float* l2_eb2  = (const float*)d_in[12];
  const float* l2_root = (const float*)d_in[13];
  const float* l2_bias = (const float*)d_in[14];

  const int* src = ei;
  const int* dst = ei + NE;

  float* P1 = (float*)d_ws;                                // [N,64] pre-relu L1 out
  unsigned short* B1  = (unsigned short*)(P1 + NN * 64);   // 2048*128 bf16 ew2 frag
  unsigned short* B2  = B1 + 2048 * 128;
  unsigned short* B1e = B2 + 2048 * 128;                   // 8*64*8 bf16 ew1 frag
  unsigned short* B2e = B1e + 8 * 64 * 8;
  float* outf = (float*)d_out;

  const int nedge_blk = (NE + 127) / 128;

  k_reorder<<<128, 256, 0, stream>>>(l1_ew2, B1);
  k_reorder<<<128, 256, 0, stream>>>(l2_ew2, B2);
  k_reorder_e<<<1, 512, 0, stream>>>(l1_ew1, B1e);
  k_reorder_e<<<1, 512, 0, stream>>>(l2_ew1, B2e);

  k_root<32, 64, false><<<(NN * 64 + 255) / 256, 256, 0, stream>>>(x, l1_root, l1_bias, P1);
  k_edge<32, 64, false><<<nedge_blk, 256, 0, stream>>>(src, dst, eattr, B1e, l1_eb1, B1, l1_eb2, x, P1);
  k_root<64, 32, true><<<(NN * 32 + 255) / 256, 256, 0, stream>>>(P1, l2_root, l2_bias, outf);
  k_edge<64, 32, true><<<nedge_blk, 256, 0, stream>>>(src, dst, eattr, B2e, l2_eb1, B2, l2_eb2, P1, outf);
}

// Round 10
// 101.043 us; speedup vs baseline: 1.4173x; 1.1381x over previous
//
#include <hip/hip_runtime.h>

#define NN 10000
#define NE 40000

typedef __attribute__((ext_vector_type(8))) short bf16x8;
typedef __attribute__((ext_vector_type(4))) float f32x4;
typedef __attribute__((ext_vector_type(8))) unsigned short u16x8;

__device__ inline unsigned short bf16rne(float f) {
  union { float f; unsigned u; } v; v.f = f;
  return (unsigned short)((v.u + 0x7FFFu + ((v.u >> 16) & 1u)) >> 16);
}

// ew2 [128 x 2048] f32 -> bf16 MFMA-B fragment order.
// elem j of lane l, col-tile ct, k-chunk kk = B[kk*32+(l>>4)*8+j][ct*16+(l&15)]
// at ushort index ct*2048 + kk*512 + l*8 + j.
__global__ void k_reorder(const float* __restrict__ ew2, unsigned short* __restrict__ out) {
  const int l  = threadIdx.x & 63;
  const int kk = threadIdx.x >> 6;
  const int ct = blockIdx.x;
  const int col = ct * 16 + (l & 15);
  const int g = l >> 4;
  u16x8 v;
#pragma unroll
  for (int j = 0; j < 8; ++j) v[j] = bf16rne(ew2[(kk * 32 + g * 8 + j) * 2048 + col]);
  *reinterpret_cast<u16x8*>(out + ((size_t)(ct * 2048 + kk * 512 + l * 8))) = v;
}

// ew1 [16 x 128] f32 -> bf16 B-frag, K padded to 32 with zeros. 8 col-tiles.
__global__ void k_reorder_e(const float* __restrict__ ew1, unsigned short* __restrict__ out) {
  const int l  = threadIdx.x & 63;
  const int ct = threadIdx.x >> 6;  // 512 threads -> 8 tiles
  const int g = l >> 4;
  u16x8 v;
#pragma unroll
  for (int j = 0; j < 8; ++j) {
    int k = g * 8 + j;
    v[j] = (k < 16) ? bf16rne(ew1[k * 128 + ct * 16 + (l & 15)]) : (unsigned short)0;
  }
  *reinterpret_cast<u16x8*>(out + ((size_t)(ct * 64 + l) * 8)) = v;
}

// out[n,KO] = (relu?)(xin[n,KI]) @ root[KI,KO] + bias[KO]
template <int KI, int KO, bool RELU_IN>
__global__ void k_root(const float* __restrict__ xin, const float* __restrict__ root,
                       const float* __restrict__ bias, float* __restrict__ out) {
  int idx = blockIdx.x * 256 + threadIdx.x;
  if (idx >= NN * KO) return;
  int n = idx / KO, o = idx % KO;
  float acc = bias[o];
#pragma unroll
  for (int k = 0; k < KI; ++k) {
    float v = xin[n * KI + k];
    if (RELU_IN) v = fmaxf(v, 0.f);
    acc += v * root[k * KO + o];
  }
  out[idx] = acc;
}

// Fused per-edge kernel: 64 edges/block, 8 waves (512 thr), 625 blocks.
// i-dimension split across waves (B traffic stays 1x, unlike the R6 m-split);
// 16-iter t-loop per wave with depth-2 register prefetch. Wave partials
// combined via 4 LDS planes (aliased over dead hfrag arena); final atomics
// use the proven coalesced pattern (16 lanes = 16 contiguous cols, 64B runs),
// one atomic per (e,ocol).
// L1 (CI=32): wave=(ot=w>>1, ih=w&1); i=ih+2t; ct=i*4+ot; 1 combine stage.
// L2 (CI=64): wave=(ot=w>>2, ip=w&3); i=ip+4t; ct=i*2+ot; 2-stage tree.
template <int CI, int CO, bool RELU_IN>
__global__ __launch_bounds__(512, 4) void k_edge(
    const int* __restrict__ src, const int* __restrict__ dst,
    const float* __restrict__ eattr,
    const unsigned short* __restrict__ ew1f, const float* __restrict__ eb1,
    const unsigned short* __restrict__ bfrag, const float* __restrict__ eb2,
    const float* __restrict__ xin, float* __restrict__ aggr) {
  constexpr int TE = 64;
  const int tid = threadIdx.x;
  const int e0 = blockIdx.x * TE;

  __shared__ int s_src[TE];
  __shared__ int s_dst[TE];
  __shared__ float s_x[CI][68];
  __shared__ float s_eb2[2048];
  __shared__ float s_arena[4 * 1088];  // 17.4 KB: hfrag (16 KB) aliases; 4 combine planes
  unsigned short* s_hfrag = reinterpret_cast<unsigned short*>(s_arena);

  if (tid < TE) { s_src[tid] = src[e0 + tid]; s_dst[tid] = dst[e0 + tid]; }
  for (int i = tid; i < CI * CO; i += 512) s_eb2[i] = eb2[i];
  __syncthreads();

  // gather x[src] -> transposed LDS
  for (int idx = tid; idx < TE * CI; idx += 512) {
    int e = idx / CI, c = idx % CI;
    float v = xin[(size_t)s_src[e] * CI + c];
    if (RELU_IN) v = fmaxf(v, 0.f);
    s_x[c][e] = v;
  }

  const int l = tid & 63, w = tid >> 6, g = l >> 4, c16 = l & 15;

  // ---- H phase via MFMA: wave w -> edge tile m=w>>1, channel half w&1
  {
    const int m = w >> 1;
    bf16x8 ea;
#pragma unroll
    for (int j = 0; j < 8; ++j) ea[j] = 0;
    if (g < 2) {
      const float* p = eattr + (size_t)(e0 + 16 * m + c16) * 16 + g * 8;
      f32x4 v0 = *reinterpret_cast<const f32x4*>(p);
      f32x4 v1 = *reinterpret_cast<const f32x4*>(p + 4);
#pragma unroll
      for (int j = 0; j < 4; ++j) { ea[j] = bf16rne(v0[j]); ea[4 + j] = bf16rne(v1[j]); }
    }
#pragma unroll
    for (int q = 0; q < 4; ++q) {
      const int ct = (w & 1) * 4 + q;
      bf16x8 bw = *reinterpret_cast<const bf16x8*>(ew1f + (size_t)(ct * 64 + l) * 8);
      const float bb = eb1[ct * 16 + c16];
      f32x4 acc = {bb, bb, bb, bb};
      acc = __builtin_amdgcn_mfma_f32_16x16x32_bf16(ea, bw, acc, 0, 0, 0);
#pragma unroll
      for (int r = 0; r < 4; ++r) {
        const int c = ct * 16 + c16;
        s_hfrag[(((m * 4) + (c >> 5)) * 64 + ((c >> 3) & 3) * 16 + g * 4 + r) * 8 + (c & 7)] =
            bf16rne(fmaxf(acc[r], 0.f));
      }
    }
  }
  __syncthreads();

  // A fragments reg-resident (linear conflict-free b128 reads)
  bf16x8 afrag[4][4];
#pragma unroll
  for (int m = 0; m < 4; ++m)
#pragma unroll
    for (int kk = 0; kk < 4; ++kk)
      afrag[m][kk] = *reinterpret_cast<const bf16x8*>(&s_hfrag[((m * 4 + kk) * 64 + l) * 8]);
  __syncthreads();  // hfrag reads done: arena reusable as combine planes

  float msg[4][4];
#pragma unroll
  for (int m = 0; m < 4; ++m)
#pragma unroll
    for (int r = 0; r < 4; ++r) msg[m][r] = 0.f;

  const int ot = (CI == 32) ? (w >> 1) : (w >> 2);
  const int ih = (CI == 32) ? (w & 1) : (w & 3);  // i-phase within split
  const int ocol = ot * 16 + c16;
  const bf16x8* Bb = reinterpret_cast<const bf16x8*>(bfrag);

  bf16x8 bA[4], bB[4];

#define PREF(T, BUF)                                                             \
  {                                                                              \
    const int i_ = (CI == 32) ? (ih + 2 * (T)) : (ih + 4 * (T));                 \
    const int ct_ = (CI == 32) ? (i_ * 4 + ot) : (i_ * 2 + ot);                  \
    const bf16x8* bp_ = Bb + (size_t)ct_ * 256 + l;                              \
    _Pragma("unroll") for (int kk = 0; kk < 4; ++kk) BUF[kk] = bp_[kk * 64];     \
  }

#define COMP(T, BUF)                                                             \
  {                                                                              \
    const int i_ = (CI == 32) ? (ih + 2 * (T)) : (ih + 4 * (T));                 \
    const float bb = s_eb2[i_ * CO + ocol];                                      \
    _Pragma("unroll") for (int m = 0; m < 4; ++m) {                              \
      f32x4 wacc = {0.f, 0.f, 0.f, 0.f};                                         \
      _Pragma("unroll") for (int kk = 0; kk < 4; ++kk)                           \
          wacc = __builtin_amdgcn_mfma_f32_16x16x32_bf16(afrag[m][kk], BUF[kk],  \
                                                         wacc, 0, 0, 0);         \
      const f32x4 xs = *reinterpret_cast<const f32x4*>(&s_x[i_][m * 16 + g * 4]);\
      _Pragma("unroll") for (int r = 0; r < 4; ++r)                              \
          msg[m][r] += fmaxf(wacc[r] + bb, 0.f) * xs[r];                         \
    }                                                                            \
  }

  PREF(0, bA)
#pragma unroll 1
  for (int t = 0; t < 14; t += 2) {
    PREF(t + 1, bB)
    COMP(t, bA)
    PREF(t + 2, bA)
    COMP(t + 1, bB)
  }
  PREF(15, bB)
  COMP(14, bA)
  COMP(15, bB)
#undef PREF
#undef COMP

  // ---- combine wave partials (planes stride 17 to spread banks)
  float* cb = s_arena;
#define PLANE_W(P)                                                               \
  _Pragma("unroll") for (int m = 0; m < 4; ++m)                                  \
  _Pragma("unroll") for (int r = 0; r < 4; ++r)                                  \
      cb[(P) * 1088 + (m * 16 + g * 4 + r) * 17 + c16] = msg[m][r];
#define PLANE_A(P)                                                               \
  _Pragma("unroll") for (int m = 0; m < 4; ++m)                                  \
  _Pragma("unroll") for (int r = 0; r < 4; ++r)                                  \
      msg[m][r] += cb[(P) * 1088 + (m * 16 + g * 4 + r) * 17 + c16];

  if (CI == 32) {
    if (ih == 1) { PLANE_W(ot) }
    __syncthreads();
    if (ih == 0) {
      PLANE_A(ot)
#pragma unroll
      for (int m = 0; m < 4; ++m)
#pragma unroll
        for (int r = 0; r < 4; ++r)
          atomicAdd(&aggr[(size_t)s_dst[m * 16 + g * 4 + r] * CO + ocol], msg[m][r]);
    }
  } else {
    if (ih >= 2) { PLANE_W(ot * 2 + (ih - 2)) }
    __syncthreads();
    if (ih < 2) { PLANE_A(ot * 2 + ih) }
    __syncthreads();
    if (ih == 1) { PLANE_W(ot * 2 + 1) }
    __syncthreads();
    if (ih == 0) {
      PLANE_A(ot * 2 + 1)
#pragma unroll
      for (int m = 0; m < 4; ++m)
#pragma unroll
        for (int r = 0; r < 4; ++r)
          atomicAdd(&aggr[(size_t)s_dst[m * 16 + g * 4 + r] * CO + ocol], msg[m][r]);
    }
  }
#undef PLANE_W
#undef PLANE_A
}

extern "C" void kernel_launch(void* const* d_in, const int* in_sizes, int n_in,
                              void* d_out, int out_size, void* d_ws, size_t ws_size,
                              hipStream_t stream) {
  const float* x       = (const float*)d_in[0];
  const int*   ei      = (const int*)d_in[1];
  const float* eattr   = (const float*)d_in[2];
  const float* l1_ew1  = (const float*)d_in[3];
  const float* l1_eb1  = (const float*)d_in[4];
  const float* l1_ew2  = (const float*)d_in[5];
  const float* l1_eb2  = (const float*)d_in[6];
  const float* l1_root = (const float*)d_in[7];
  const float* l1_bias = (const float*)d_in[8];
  const float* l2_ew1  = (const float*)d_in[9];
  const float* l2_eb1  = (const float*)d_in[10];
  const float* l2_ew2  = (const float*)d_in[11];
  const float* l2_eb2  = (const float*)d_in[12];
  const float* l2_root = (const float*)d_in[13];
  const float* l2_bias = (const float*)d_in[14];

  const int* src = ei;
  const int* dst = ei + NE;

  float* P1 = (float*)d_ws;                                // [N,64] pre-relu L1 out
  unsigned short* B1  = (unsigned short*)(P1 + NN * 64);   // 2048*128 bf16 ew2 frag
  unsigned short* B2  = B1 + 2048 * 128;
  unsigned short* B1e = B2 + 2048 * 128;                   // 8*64*8 bf16 ew1 frag
  unsigned short* B2e = B1e + 8 * 64 * 8;
  float* outf = (float*)d_out;

  k_reorder<<<128, 256, 0, stream>>>(l1_ew2, B1);
  k_reorder<<<128, 256, 0, stream>>>(l2_ew2, B2);
  k_reorder_e<<<1, 512, 0, stream>>>(l1_ew1, B1e);
  k_reorder_e<<<1, 512, 0, stream>>>(l2_ew1, B2e);

  k_root<32, 64, false><<<(NN * 64 + 255) / 256, 256, 0, stream>>>(x, l1_root, l1_bias, P1);
  k_edge<32, 64, false><<<NE / 64, 512, 0, stream>>>(src, dst, eattr, B1e, l1_eb1, B1, l1_eb2, x, P1);
  k_root<64, 32, true><<<(NN * 32 + 255) / 256, 256, 0, stream>>>(P1, l2_root, l2_bias, outf);
  k_edge<64, 32, true><<<NE / 64, 512, 0, stream>>>(src, dst, eattr, B2e, l2_eb1, B2, l2_eb2, P1, outf);
}

// Round 11
// 97.518 us; speedup vs baseline: 1.4685x; 1.0361x over previous
//
#include <hip/hip_runtime.h>

#define NN 10000
#define NE 40000

typedef __attribute__((ext_vector_type(8))) short bf16x8;
typedef __attribute__((ext_vector_type(4))) float f32x4;
typedef __attribute__((ext_vector_type(8))) unsigned short u16x8;

__device__ inline unsigned short bf16rne(float f) {
  union { float f; unsigned u; } v; v.f = f;
  return (unsigned short)((v.u + 0x7FFFu + ((v.u >> 16) & 1u)) >> 16);
}

// ew2 [128 x 2048] f32 -> bf16 MFMA-B fragment order.
// elem j of lane l, col-tile ct, k-chunk kk = B[kk*32+(l>>4)*8+j][ct*16+(l&15)]
// at ushort index ct*2048 + kk*512 + l*8 + j.
__global__ void k_reorder(const float* __restrict__ ew2, unsigned short* __restrict__ out) {
  const int l  = threadIdx.x & 63;
  const int kk = threadIdx.x >> 6;
  const int ct = blockIdx.x;
  const int col = ct * 16 + (l & 15);
  const int g = l >> 4;
  u16x8 v;
#pragma unroll
  for (int j = 0; j < 8; ++j) v[j] = bf16rne(ew2[(kk * 32 + g * 8 + j) * 2048 + col]);
  *reinterpret_cast<u16x8*>(out + ((size_t)(ct * 2048 + kk * 512 + l * 8))) = v;
}

// ew1 [16 x 128] f32 -> bf16 B-frag, K padded to 32 with zeros. 8 col-tiles.
__global__ void k_reorder_e(const float* __restrict__ ew1, unsigned short* __restrict__ out) {
  const int l  = threadIdx.x & 63;
  const int ct = threadIdx.x >> 6;  // 512 threads -> 8 tiles
  const int g = l >> 4;
  u16x8 v;
#pragma unroll
  for (int j = 0; j < 8; ++j) {
    int k = g * 8 + j;
    v[j] = (k < 16) ? bf16rne(ew1[k * 128 + ct * 16 + (l & 15)]) : (unsigned short)0;
  }
  *reinterpret_cast<u16x8*>(out + ((size_t)(ct * 64 + l) * 8)) = v;
}

// out[n,KO] = (relu?)(xin[n,KI]) @ root[KI,KO] + bias[KO]
template <int KI, int KO, bool RELU_IN>
__global__ void k_root(const float* __restrict__ xin, const float* __restrict__ root,
                       const float* __restrict__ bias, float* __restrict__ out) {
  int idx = blockIdx.x * 256 + threadIdx.x;
  if (idx >= NN * KO) return;
  int n = idx / KO, o = idx % KO;
  float acc = bias[o];
#pragma unroll
  for (int k = 0; k < KI; ++k) {
    float v = xin[n * KI + k];
    if (RELU_IN) v = fmaxf(v, 0.f);
    acc += v * root[k * KO + o];
  }
  out[idx] = acc;
}

// Fused per-edge kernel: 64 edges/block, 4 waves (R3 structure).
// CHANGE vs R3: COMP restructured kk-outer/m-inner with split accumulators
// (8 independent MFMA chains, depth 2) to break the serial MFMA dependency
// chain; zero-init folded into the first MFMA's C operand (vzero).
// eb2 staged in LDS so loop VMEM is exactly the 4 B-fragment loads.
template <int CI, int CO, bool RELU_IN>
__global__ __launch_bounds__(256, 2) void k_edge(
    const int* __restrict__ src, const int* __restrict__ dst,
    const float* __restrict__ eattr,
    const unsigned short* __restrict__ ew1f, const float* __restrict__ eb1,
    const unsigned short* __restrict__ bfrag, const float* __restrict__ eb2,
    const float* __restrict__ xin, float* __restrict__ aggr) {
  constexpr int TE = 64;
  const int tid = threadIdx.x;
  const int e0 = blockIdx.x * TE;

  __shared__ int s_src[TE];
  __shared__ int s_dst[TE];
  __shared__ float s_x[CI][68];
  __shared__ float s_eb2[2048];
  __shared__ unsigned short s_hfrag[16 * 64 * 8];  // 16 KB

  if (tid < TE) { s_src[tid] = src[e0 + tid]; s_dst[tid] = dst[e0 + tid]; }
  for (int i = tid; i < CI * CO; i += 256) s_eb2[i] = eb2[i];
  __syncthreads();

  // gather x[src] -> transposed LDS
  for (int idx = tid; idx < TE * CI; idx += 256) {
    int e = idx / CI, c = idx % CI;
    float v = xin[(size_t)s_src[e] * CI + c];
    if (RELU_IN) v = fmaxf(v, 0.f);
    s_x[c][e] = v;
  }

  const int l = tid & 63, w = tid >> 6, g = l >> 4, c16 = l & 15;

  // ---- H phase via MFMA: wave w -> edge tile m=w, all 128 channels (8 MFMAs)
  {
    const int m = w;
    bf16x8 ea;
#pragma unroll
    for (int j = 0; j < 8; ++j) ea[j] = 0;
    if (g < 2) {
      const float* p = eattr + (size_t)(e0 + 16 * m + c16) * 16 + g * 8;
      f32x4 v0 = *reinterpret_cast<const f32x4*>(p);
      f32x4 v1 = *reinterpret_cast<const f32x4*>(p + 4);
#pragma unroll
      for (int j = 0; j < 4; ++j) { ea[j] = bf16rne(v0[j]); ea[4 + j] = bf16rne(v1[j]); }
    }
#pragma unroll
    for (int ct = 0; ct < 8; ++ct) {
      bf16x8 bw = *reinterpret_cast<const bf16x8*>(ew1f + (size_t)(ct * 64 + l) * 8);
      const float bb = eb1[ct * 16 + c16];
      f32x4 acc = {bb, bb, bb, bb};
      acc = __builtin_amdgcn_mfma_f32_16x16x32_bf16(ea, bw, acc, 0, 0, 0);
#pragma unroll
      for (int r = 0; r < 4; ++r) {
        const int c = ct * 16 + c16;
        s_hfrag[(((m * 4) + (c >> 5)) * 64 + ((c >> 3) & 3) * 16 + g * 4 + r) * 8 + (c & 7)] =
            bf16rne(fmaxf(acc[r], 0.f));
      }
    }
  }
  __syncthreads();

  // A fragments reg-resident (linear conflict-free b128 reads)
  bf16x8 afrag[4][4];
#pragma unroll
  for (int m = 0; m < 4; ++m)
#pragma unroll
    for (int kk = 0; kk < 4; ++kk)
      afrag[m][kk] = *reinterpret_cast<const bf16x8*>(&s_hfrag[((m * 4 + kk) * 64 + l) * 8]);

  float msg[4][4];
#pragma unroll
  for (int m = 0; m < 4; ++m)
#pragma unroll
    for (int r = 0; r < 4; ++r) msg[m][r] = 0.f;

  // per-wave t-schedule (R3):
  // L1 (CI=32): i=t, ct=t*4+w, ocol=w*16+c16
  // L2 (CI=64): i=(w>>1)+2t, ct=i*2+(w&1), ocol=(w&1)*16+c16 (i-parity split)
  const int ocol = (CI == 32) ? (w * 16 + c16) : ((w & 1) * 16 + c16);
  const bf16x8* Bb = reinterpret_cast<const bf16x8*>(bfrag);
  const f32x4 vzero = {0.f, 0.f, 0.f, 0.f};

  bf16x8 bA[4], bB[4];

#define PREF(T, BUF)                                                             \
  {                                                                              \
    const int i_ = (CI == 32) ? (T) : ((w >> 1) + 2 * (T));                      \
    const int ct_ = (CI == 32) ? ((T) * 4 + w) : (i_ * 2 + (w & 1));             \
    const bf16x8* bp_ = Bb + (size_t)ct_ * 256 + l;                              \
    _Pragma("unroll") for (int kk = 0; kk < 4; ++kk) BUF[kk] = bp_[kk * 64];     \
  }

// kk-outer / m-inner: 8 independent MFMA chains (acc0: kk 0,1; acc1: kk 2,3),
// chain depth 2, first MFMA consumes vzero as C (no per-iter zero-init).
#define COMP(T, BUF)                                                             \
  {                                                                              \
    const int i_ = (CI == 32) ? (T) : ((w >> 1) + 2 * (T));                      \
    const float bb = s_eb2[i_ * CO + ocol];                                      \
    f32x4 acc0[4], acc1[4];                                                      \
    _Pragma("unroll") for (int m = 0; m < 4; ++m)                                \
        acc0[m] = __builtin_amdgcn_mfma_f32_16x16x32_bf16(afrag[m][0], BUF[0],   \
                                                          vzero, 0, 0, 0);       \
    _Pragma("unroll") for (int m = 0; m < 4; ++m)                                \
        acc1[m] = __builtin_amdgcn_mfma_f32_16x16x32_bf16(afrag[m][2], BUF[2],   \
                                                          vzero, 0, 0, 0);       \
    _Pragma("unroll") for (int m = 0; m < 4; ++m)                                \
        acc0[m] = __builtin_amdgcn_mfma_f32_16x16x32_bf16(afrag[m][1], BUF[1],   \
                                                          acc0[m], 0, 0, 0);     \
    _Pragma("unroll") for (int m = 0; m < 4; ++m)                                \
        acc1[m] = __builtin_amdgcn_mfma_f32_16x16x32_bf16(afrag[m][3], BUF[3],   \
                                                          acc1[m], 0, 0, 0);     \
    _Pragma("unroll") for (int m = 0; m < 4; ++m) {                              \
      const f32x4 xs = *reinterpret_cast<const f32x4*>(&s_x[i_][m * 16 + g * 4]);\
      _Pragma("unroll") for (int r = 0; r < 4; ++r)                              \
          msg[m][r] += fmaxf(acc0[m][r] + acc1[m][r] + bb, 0.f) * xs[r];         \
    }                                                                            \
  }

  PREF(0, bA)
#pragma unroll 1
  for (int t = 0; t < 30; t += 2) {
    PREF(t + 1, bB)
    COMP(t, bA)
    PREF(t + 2, bA)
    COMP(t + 1, bB)
  }
  PREF(31, bB)
  COMP(30, bA)
  COMP(31, bB)
#undef PREF
#undef COMP

  // coalesced atomics: per instruction, 4 edges x 16 consecutive cols (64B runs)
#pragma unroll
  for (int m = 0; m < 4; ++m)
#pragma unroll
    for (int r = 0; r < 4; ++r)
      atomicAdd(&aggr[(size_t)s_dst[m * 16 + g * 4 + r] * CO + ocol], msg[m][r]);
}

extern "C" void kernel_launch(void* const* d_in, const int* in_sizes, int n_in,
                              void* d_out, int out_size, void* d_ws, size_t ws_size,
                              hipStream_t stream) {
  const float* x       = (const float*)d_in[0];
  const int*   ei      = (const int*)d_in[1];
  const float* eattr   = (const float*)d_in[2];
  const float* l1_ew1  = (const float*)d_in[3];
  const float* l1_eb1  = (const float*)d_in[4];
  const float* l1_ew2  = (const float*)d_in[5];
  const float* l1_eb2  = (const float*)d_in[6];
  const float* l1_root = (const float*)d_in[7];
  const float* l1_bias = (const float*)d_in[8];
  const float* l2_ew1  = (const float*)d_in[9];
  const float* l2_eb1  = (const float*)d_in[10];
  const float* l2_ew2  = (const float*)d_in[11];
  const float* l2_eb2  = (const float*)d_in[12];
  const float* l2_root = (const float*)d_in[13];
  const float* l2_bias = (const float*)d_in[14];

  const int* src = ei;
  const int* dst = ei + NE;

  float* P1 = (float*)d_ws;                                // [N,64] pre-relu L1 out
  unsigned short* B1  = (unsigned short*)(P1 + NN * 64);   // 2048*128 bf16 ew2 frag
  unsigned short* B2  = B1 + 2048 * 128;
  unsigned short* B1e = B2 + 2048 * 128;                   // 8*64*8 bf16 ew1 frag
  unsigned short* B2e = B1e + 8 * 64 * 8;
  float* outf = (float*)d_out;

  k_reorder<<<128, 256, 0, stream>>>(l1_ew2, B1);
  k_reorder<<<128, 256, 0, stream>>>(l2_ew2, B2);
  k_reorder_e<<<1, 512, 0, stream>>>(l1_ew1, B1e);
  k_reorder_e<<<1, 512, 0, stream>>>(l2_ew1, B2e);

  k_root<32, 64, false><<<(NN * 64 + 255) / 256, 256, 0, stream>>>(x, l1_root, l1_bias, P1);
  k_edge<32, 64, false><<<NE / 64, 256, 0, stream>>>(src, dst, eattr, B1e, l1_eb1, B1, l1_eb2, x, P1);
  k_root<64, 32, true><<<(NN * 32 + 255) / 256, 256, 0, stream>>>(P1, l2_root, l2_bias, outf);
  k_edge<64, 32, true><<<NE / 64, 256, 0, stream>>>(src, dst, eattr, B2e, l2_eb1, B2, l2_eb2, P1, outf);
}